// Round 8
// baseline (478.396 us; speedup 1.0000x reference)
//
#include <hip/hip_runtime.h>
#include <hip/hip_bf16.h>
#include <cfloat>

#define N_NODES 50000
#define N_EDGES 800000
#define N_GRAPHS 50
#define FEAT 256
#define NEG_SLOPE 0.2f

#define NBUCKET 391   // ceil(50000/128); bucket b = dst >> 7
#define BCAP 3072     // capacity per bucket (mean 2046, sd ~45)
#define P1_EDGES 8192
#define P1_BLOCKS 98  // 98*8192 = 802816 >= 800000

typedef __attribute__((ext_vector_type(8))) short short8;
typedef __attribute__((ext_vector_type(4))) short shortx4;
typedef __attribute__((ext_vector_type(4))) float floatx4;

constexpr int GY = (N_NODES + 127) / 128;  // 391 gemm y-rows

__device__ __forceinline__ float lrelu(float e) {
  return e > 0.f ? e : NEG_SLOPE * e;
}
__device__ __forceinline__ short f2bf(float f) {
  __hip_bfloat16 b = __float2bfloat16(f);
  return *(short*)&b;
}
__device__ __forceinline__ float bf2f(short s) {
  unsigned u = ((unsigned)(unsigned short)s) << 16;
  return __uint_as_float(u);
}

// ---- W prep (blocks 0..511) + pass-1 edge binning (blocks 512..609) ----
__global__ __launch_bounds__(256) void wsplit_pass1_kernel(
    const float* __restrict__ W1, const float* __restrict__ W2,
    short* __restrict__ H1, short* __restrict__ L1,
    short* __restrict__ H2, short* __restrict__ L2,
    const int* __restrict__ src, const int* __restrict__ dst,
    int* __restrict__ gbcnt, int* __restrict__ bdata) {
  int b = blockIdx.x, t = threadIdx.x;
  if (b < 512) {
    const float* W = (b < 256) ? W1 : W2;
    short* Hp = (b < 256) ? H1 : H2;
    short* Lp = (b < 256) ? L1 : L2;
    int k = b & 255;
    float v = W[k * 256 + t];
    short h = f2bf(v);
    Hp[t * 256 + k] = h;
    Lp[t * 256 + k] = f2bf(v - bf2f(h));
    return;
  }
  __shared__ int bb[NBUCKET];
  int base = (b - 512) * P1_EDGES;
  for (int i = t; i < NBUCKET; i += 256) bb[i] = 0;
  __syncthreads();
#pragma unroll 4
  for (int j = 0; j < P1_EDGES / 256; j++) {
    int e = base + j * 256 + t;
    if (e < N_EDGES) atomicAdd(&bb[dst[e] >> 7], 1);
  }
  __syncthreads();
  for (int i = t; i < NBUCKET; i += 256) {
    int c = bb[i];
    bb[i] = (c > 0) ? atomicAdd(&gbcnt[i], c) : 0;
  }
  __syncthreads();
#pragma unroll 4
  for (int j = 0; j < P1_EDGES / 256; j++) {
    int e = base + j * 256 + t;
    if (e < N_EDGES) {
      int d = dst[e];
      int bk = d >> 7;
      int p = atomicAdd(&bb[bk], 1);
      if (p < BCAP) bdata[bk * BCAP + p] = (src[e] << 7) | (d & 127);
    }
  }
}

// ---- exclusive scan of 391 bucket counts + graph bounds ----
__global__ __launch_bounds__(256) void bucketscan_kernel(
    const int* __restrict__ gbcnt, int* __restrict__ gboffs,
    int* __restrict__ offs, const int* __restrict__ batch,
    int* __restrict__ gstart) {
  __shared__ int s[512];
  int t = threadIdx.x;
  s[t] = (t < NBUCKET) ? gbcnt[t] : 0;
  s[t + 256] = (t + 256 < NBUCKET) ? gbcnt[t + 256] : 0;
  __syncthreads();
  for (int off = 1; off < 512; off <<= 1) {
    int v0 = (t >= off) ? s[t - off] : 0;
    int v1 = (t + 256 >= off) ? s[t + 256 - off] : 0;
    __syncthreads();
    s[t] += v0;
    s[t + 256] += v1;
    __syncthreads();
  }
  if (t < NBUCKET) gboffs[t] = (t == 0) ? 0 : s[t - 1];
  if (t + 256 < NBUCKET) gboffs[t + 256] = s[t + 255];
  if (t == 0) {
    gboffs[NBUCKET] = s[NBUCKET - 1];
    offs[N_NODES] = s[NBUCKET - 1];
  }
  if (t <= N_GRAPHS) {
    int lo = 0, hi = N_NODES;
    while (lo < hi) {
      int mid = (lo + hi) >> 1;
      if (batch[mid] < t) lo = mid + 1; else hi = mid;
    }
    gstart[t] = lo;
  }
}

// ---- MFMA GEMM + fused attention dots; tail scatter (R14 verified) ----
template <int H, bool SCATTER, bool SPLIT_IN>
__global__ __launch_bounds__(256) void gemm_mfma_kernel(
    const float* __restrict__ A, const short* __restrict__ AH,
    const short* __restrict__ AL,
    const short* __restrict__ WtH, const short* __restrict__ WtL,
    short* __restrict__ C16,
    const float* __restrict__ att_src, const float* __restrict__ att_dst,
    float* __restrict__ a_src, float* __restrict__ a_dst, int M,
    const int* __restrict__ bdata, const int* __restrict__ gbcnt,
    const int* __restrict__ gboffs, int* __restrict__ offs,
    int* __restrict__ ssrc) {
  __shared__ __align__(16) char smem[32768];
  auto AsH = (short(*)[32])(smem);
  auto AsL = (short(*)[32])(smem + 8192);
  auto BsH = (short(*)[32])(smem + 16384);
  auto BsL = (short(*)[32])(smem + 24576);
  int t = threadIdx.x;
  int yb = blockIdx.y;
  if constexpr (SCATTER) {
    if (yb >= GY) {
      int bkt = (yb - GY) * 2 + blockIdx.x;  // 0..391
      if (bkt >= NBUCKET) return;
      int nbase = bkt * 128;
      int nn = N_NODES - nbase; if (nn > 128) nn = 128;
      int cb = gbcnt[bkt]; if (cb > BCAP) cb = BCAP;
      int gb = gboffs[bkt];
      int* hist = (int*)smem;        // [128]
      int* cur = hist + 128;         // [128]
      int* stage = cur + 128;        // [3072]
      if (t < 128) hist[t] = 0;
      __syncthreads();
      const int* bd = bdata + bkt * BCAP;
      for (int i = t; i < cb; i += 256) atomicAdd(&hist[bd[i] & 127], 1);
      __syncthreads();
      if (t < 128) cur[t] = hist[t];
      __syncthreads();
      for (int off = 1; off < 128; off <<= 1) {
        int v = (t >= off && t < 128) ? cur[t - off] : 0;
        __syncthreads();
        if (t < 128) cur[t] += v;
        __syncthreads();
      }
      if (t < 128) {
        int excl = cur[t] - hist[t];
        if (t < nn) offs[nbase + t] = gb + excl;
        cur[t] = excl;  // local cursor
      }
      __syncthreads();
      for (int i = t; i < cb; i += 256) {
        int w = bd[i];
        int p = atomicAdd(&cur[w & 127], 1);
        stage[p] = w >> 7;
      }
      __syncthreads();
      for (int i = t; i < cb; i += 256) ssrc[gb + i] = stage[i];
      return;
    }
  }
  int bm = yb * 128, bn = blockIdx.x * 128;
  int w = t >> 6, lane = t & 63;
  int wrow = (w & 1) * 64, wcol = (w >> 1) * 64;
  int m15 = lane & 15, q = lane >> 4;
  int sr = t >> 1, sk = (t & 1) * 16;
  int g3 = (sr >> 1) & 3;
  int c0 = (((sk >> 3) + 0) ^ g3) * 8;
  int c1 = (((sk >> 3) + 1) ^ g3) * 8;
  floatx4 acc[4][4] = {};
  int arow = bm + sr;
  for (int k0 = 0; k0 < 256; k0 += 32) {
    int4 ah0, ah1, al0, al1;
    if constexpr (SPLIT_IN) {
      if (arow < M) {
        const short* Hp = AH + (size_t)arow * 256 + k0 + sk;
        const short* Lp = AL + (size_t)arow * 256 + k0 + sk;
        ah0 = *(const int4*)(Hp + 0);
        ah1 = *(const int4*)(Hp + 8);
        al0 = *(const int4*)(Lp + 0);
        al1 = *(const int4*)(Lp + 8);
      } else {
        ah0 = ah1 = al0 = al1 = make_int4(0, 0, 0, 0);
      }
    } else {
      float4 a0 = make_float4(0.f, 0.f, 0.f, 0.f), a1 = a0, a2 = a0, a3 = a0;
      if (arow < M) {
        const float* Ap = A + (size_t)arow * 256 + k0 + sk;
        a0 = *(const float4*)(Ap + 0);
        a1 = *(const float4*)(Ap + 4);
        a2 = *(const float4*)(Ap + 8);
        a3 = *(const float4*)(Ap + 12);
      }
      float af[16];
      *(float4*)&af[0] = a0; *(float4*)&af[4] = a1;
      *(float4*)&af[8] = a2; *(float4*)&af[12] = a3;
      short th[16], tl[16];
#pragma unroll
      for (int j = 0; j < 16; j++) {
        short h = f2bf(af[j]);
        th[j] = h;
        tl[j] = f2bf(af[j] - bf2f(h));
      }
      ah0 = *(int4*)&th[0]; ah1 = *(int4*)&th[8];
      al0 = *(int4*)&tl[0]; al1 = *(int4*)&tl[8];
    }
    const short* BHp = WtH + (size_t)(bn + sr) * 256 + k0 + sk;
    const short* BLp = WtL + (size_t)(bn + sr) * 256 + k0 + sk;
    int4 bh0 = *(const int4*)(BHp);
    int4 bh1 = *(const int4*)(BHp + 8);
    int4 bl0 = *(const int4*)(BLp);
    int4 bl1 = *(const int4*)(BLp + 8);
    __syncthreads();
    *(int4*)&AsH[sr][c0] = ah0;
    *(int4*)&AsH[sr][c1] = ah1;
    *(int4*)&AsL[sr][c0] = al0;
    *(int4*)&AsL[sr][c1] = al1;
    *(int4*)&BsH[sr][c0] = bh0;
    *(int4*)&BsH[sr][c1] = bh1;
    *(int4*)&BsL[sr][c0] = bl0;
    *(int4*)&BsL[sr][c1] = bl1;
    __syncthreads();
    short8 Bh[4], Bl[4];
#pragma unroll
    for (int c = 0; c < 4; c++) {
      int Rb = wcol + c * 16 + m15;
      int sw = (q ^ ((Rb >> 1) & 3)) * 8;
      Bh[c] = *(const short8*)&BsH[Rb][sw];
      Bl[c] = *(const short8*)&BsL[Rb][sw];
    }
#pragma unroll
    for (int r = 0; r < 4; r++) {
      int Ra = wrow + r * 16 + m15;
      int sw = (q ^ ((Ra >> 1) & 3)) * 8;
      short8 Ah = *(const short8*)&AsH[Ra][sw];
      short8 Al = *(const short8*)&AsL[Ra][sw];
#pragma unroll
      for (int c = 0; c < 4; c++) {
        acc[r][c] = __builtin_amdgcn_mfma_f32_16x16x32_bf16(Ah, Bh[c], acc[r][c], 0, 0, 0);
        acc[r][c] = __builtin_amdgcn_mfma_f32_16x16x32_bf16(Ah, Bl[c], acc[r][c], 0, 0, 0);
        acc[r][c] = __builtin_amdgcn_mfma_f32_16x16x32_bf16(Al, Bh[c], acc[r][c], 0, 0, 0);
      }
    }
  }
  float asv[4], adv[4];
#pragma unroll
  for (int c = 0; c < 4; c++) {
    int col = bn + wcol + c * 16 + m15;
    asv[c] = att_src[col];
    adv[c] = att_dst[col];
  }
#pragma unroll
  for (int r = 0; r < 4; r++) {
#pragma unroll
    for (int p = 0; p < 4; p++) {
      int grow = bm + wrow + r * 16 + q * 4 + p;
      float s = acc[r][0][p] * asv[0] + acc[r][1][p] * asv[1] +
                acc[r][2][p] * asv[2] + acc[r][3][p] * asv[3];
      float d = acc[r][0][p] * adv[0] + acc[r][1][p] * adv[1] +
                acc[r][2][p] * adv[2] + acc[r][3][p] * adv[3];
#pragma unroll
      for (int o = 1; o < 16; o <<= 1) {
        s += __shfl_xor(s, o, 64);
        d += __shfl_xor(d, o, 64);
      }
      if (grow < M) {
        if (m15 == 0) {
          if constexpr (H == 4) {
            int head = (bn >> 6) + (wcol >> 6);
            a_src[grow * 4 + head] = s;
            a_dst[grow * 4 + head] = d;
          } else {
            atomicAdd(&a_src[grow], s);
            atomicAdd(&a_dst[grow], d);
          }
        }
#pragma unroll
        for (int c = 0; c < 4; c++) {
          int gcol = bn + wcol + c * 16 + m15;
          C16[(size_t)grow * 256 + gcol] = f2bf(acc[r][c][p]);
        }
      }
    }
  }
}

// ---- fused aggregate: in-register softmax, 2-deep group pipeline ----
// R15: agg was the top dispatch (70us, VALUBusy 48%, BW 58% achievable,
// nothing saturated -> gather-latency-bound). Pipeline at 8-edge-group
// granularity: ssrc prefetched TWO groups ahead (breaks the s->gather
// serial chain), h16/a_src gathers issued ONE group ahead, so compute(k)
// covers gather(k+1) latency. Outputs stored nontemporal (consumed only
// next dispatch, from L3 either way) so they don't evict gather lines.
// (nontemporal builtin needs clang ext_vector types, not HIP float4.)
template <int CH, bool SPLIT_OUT>
__global__ __launch_bounds__(256) void agg_kernel(
    const short* __restrict__ h16, const float* __restrict__ a_src,
    const float* __restrict__ a_dst, const int* __restrict__ offs,
    const int* __restrict__ ssrc, const float* __restrict__ bias,
    float* __restrict__ out, short* __restrict__ outH,
    short* __restrict__ outL, float* __restrict__ z1,
    float* __restrict__ z2) {
  constexpr int H = 256 / CH;
  int n = blockIdx.x * 4 + (threadIdx.x >> 6);
  int lane = threadIdx.x & 63;
  if (n >= N_NODES) return;
  int head = (4 * lane) / CH;
  int start = offs[n], end = offs[n + 1];
  float adv = a_dst[n * H + head];
  if (z1 != nullptr && lane == 0) { z1[n] = 0.f; z2[n] = 0.f; }
  float l = 0.f;
  float acc0 = 0.f, acc1 = 0.f, acc2 = 0.f, acc3 = 0.f;
  int i = start;
  int nfull = (end - start) >> 3;

  if (nfull > 0) {
    uint2 uC[8]; float avC[8]; int sN[8];
    {
      int sC[8];
#pragma unroll
      for (int j = 0; j < 8; j++) sC[j] = ssrc[i + j];
#pragma unroll
      for (int j = 0; j < 8; j++)
        uC[j] = *(const uint2*)(h16 + (size_t)sC[j] * 256 + 4 * lane);
#pragma unroll
      for (int j = 0; j < 8; j++) avC[j] = a_src[sC[j] * H + head];
    }
    if (nfull > 1) {
#pragma unroll
      for (int j = 0; j < 8; j++) sN[j] = ssrc[i + 8 + j];
    }
    for (int g = 0; g < nfull; g++) {
      uint2 uN[8]; float avN[8]; int sF[8];
      bool hasN = (g + 1 < nfull);
      bool hasF = (g + 2 < nfull);
      if (hasF) {
#pragma unroll
        for (int j = 0; j < 8; j++) sF[j] = ssrc[i + 16 + j];
      }
      if (hasN) {
#pragma unroll
        for (int j = 0; j < 8; j++)
          uN[j] = *(const uint2*)(h16 + (size_t)sN[j] * 256 + 4 * lane);
#pragma unroll
        for (int j = 0; j < 8; j++) avN[j] = a_src[sN[j] * H + head];
      }
#pragma unroll
      for (int j = 0; j < 8; j++) {
        float p = __expf(lrelu(avC[j] + adv));
        l += p;
        acc0 = fmaf(p, __uint_as_float(uC[j].x << 16), acc0);
        acc1 = fmaf(p, __uint_as_float(uC[j].x & 0xffff0000u), acc1);
        acc2 = fmaf(p, __uint_as_float(uC[j].y << 16), acc2);
        acc3 = fmaf(p, __uint_as_float(uC[j].y & 0xffff0000u), acc3);
      }
      if (hasN) {
#pragma unroll
        for (int j = 0; j < 8; j++) { uC[j] = uN[j]; avC[j] = avN[j]; }
        if (hasF) {
#pragma unroll
          for (int j = 0; j < 8; j++) sN[j] = sF[j];
        }
      }
      i += 8;
    }
  }
  for (; i < end; i++) {
    int s = ssrc[i];
    uint2 u = *(const uint2*)(h16 + (size_t)s * 256 + 4 * lane);
    float p = __expf(lrelu(a_src[s * H + head] + adv));
    l += p;
    acc0 = fmaf(p, __uint_as_float(u.x << 16), acc0);
    acc1 = fmaf(p, __uint_as_float(u.x & 0xffff0000u), acc1);
    acc2 = fmaf(p, __uint_as_float(u.y << 16), acc2);
    acc3 = fmaf(p, __uint_as_float(u.y & 0xffff0000u), acc3);
  }
  float ilv = l > 0.f ? 1.f / l : 0.f;
  float4 bv = *(const float4*)(bias + 4 * lane);
  float ox = fmaxf(fmaf(acc0, ilv, bv.x), 0.f);
  float oy = fmaxf(fmaf(acc1, ilv, bv.y), 0.f);
  float oz = fmaxf(fmaf(acc2, ilv, bv.z), 0.f);
  float ow = fmaxf(fmaf(acc3, ilv, bv.w), 0.f);
  if constexpr (SPLIT_OUT) {
    shortx4 hv, lv;
    hv.x = f2bf(ox); lv.x = f2bf(ox - bf2f(hv.x));
    hv.y = f2bf(oy); lv.y = f2bf(oy - bf2f(hv.y));
    hv.z = f2bf(oz); lv.z = f2bf(oz - bf2f(hv.z));
    hv.w = f2bf(ow); lv.w = f2bf(ow - bf2f(hv.w));
    __builtin_nontemporal_store(hv, (shortx4*)(outH + (size_t)n * 256 + 4 * lane));
    __builtin_nontemporal_store(lv, (shortx4*)(outL + (size_t)n * 256 + 4 * lane));
  } else {
    floatx4 o;
    o.x = ox; o.y = oy; o.z = oz; o.w = ow;
    __builtin_nontemporal_store(o, (floatx4*)(out + (size_t)n * 256 + 4 * lane));
  }
}

// ---- global mean pool + FC ----
#define POOL_PARTS 16
__global__ __launch_bounds__(256) void pool_partial_kernel(
    const float* __restrict__ h, const int* __restrict__ gstart,
    float* __restrict__ part) {
  int g = blockIdx.x, p = blockIdx.y, t = threadIdx.x;
  int s = gstart[g], e = gstart[g + 1];
  float acc = 0.f;
  for (int n = s + p; n < e; n += POOL_PARTS) acc += h[(size_t)n * 256 + t];
  part[((size_t)g * POOL_PARTS + p) * 256 + t] = acc;
}

__global__ __launch_bounds__(256) void poolfc_kernel(
    const float* __restrict__ part, const int* __restrict__ gstart,
    const float* __restrict__ W, const float* __restrict__ b,
    float* __restrict__ out) {
  int g = blockIdx.x, t = threadIdx.x;
  __shared__ float ps[256];
  float acc = 0.f;
#pragma unroll
  for (int p = 0; p < POOL_PARTS; p++)
    acc += part[((size_t)g * POOL_PARTS + p) * 256 + t];
  int cnt = gstart[g + 1] - gstart[g];
  ps[t] = acc / (float)(cnt > 0 ? cnt : 1);
  __syncthreads();
  float a2 = 0.f;
#pragma unroll 8
  for (int k = 0; k < 256; k++) a2 = fmaf(ps[k], W[k * 256 + t], a2);
  out[g * 256 + t] = fmaxf(a2 + b[t], 0.f);
}

extern "C" void kernel_launch(void* const* d_in, const int* in_sizes, int n_in,
                              void* d_out, int out_size, void* d_ws, size_t ws_size,
                              hipStream_t stream) {
  const float* x      = (const float*)d_in[0];
  const int*   ei     = (const int*)d_in[1];
  const int*   batch  = (const int*)d_in[2];
  const float* W1     = (const float*)d_in[3];
  const float* att_s1 = (const float*)d_in[4];
  const float* att_d1 = (const float*)d_in[5];
  const float* b1     = (const float*)d_in[6];
  const float* W2     = (const float*)d_in[7];
  const float* att_s2 = (const float*)d_in[8];
  const float* att_d2 = (const float*)d_in[9];
  const float* b2     = (const float*)d_in[10];
  const float* Wfc    = (const float*)d_in[11];
  const float* bfc    = (const float*)d_in[12];
  const int* src = ei;
  const int* dst = ei + N_EDGES;
  float* outp = (float*)d_out;

  char* ws = (char*)d_ws;
  size_t off = 0;
  auto alloc = [&](size_t bytes) -> char* {
    char* p = ws + off;
    off += (bytes + 255) & ~(size_t)255;
    return p;
  };
  float* x2_buf = (float*)alloc((size_t)N_NODES * FEAT * 4);
  short* h16    = (short*)alloc((size_t)N_NODES * FEAT * 2);
  float* as_buf = (float*)alloc((size_t)N_NODES * 4 * 4);
  float* ad_buf = (float*)alloc((size_t)N_NODES * 4 * 4);
  float* as2    = (float*)alloc((size_t)N_NODES * 4);
  float* ad2    = (float*)alloc((size_t)N_NODES * 4);
  float* part   = (float*)alloc((size_t)N_GRAPHS * POOL_PARTS * FEAT * 4);
  short* WtH1   = (short*)alloc((size_t)256 * 256 * 2);
  short* WtL1   = (short*)alloc((size_t)256 * 256 * 2);
  short* WtH2   = (short*)alloc((size_t)256 * 256 * 2);
  short* WtL2   = (short*)alloc((size_t)256 * 256 * 2);
  int* offs   = (int*)alloc((size_t)(N_NODES + 1) * 4);
  int* ssrc   = (int*)alloc((size_t)N_EDGES * 4);
  int* bdata  = (int*)alloc((size_t)NBUCKET * BCAP * 4);
  int* gbcnt  = (int*)alloc((size_t)(NBUCKET + 1) * 4);
  int* gboffs = (int*)alloc((size_t)(NBUCKET + 1) * 4);
  int* gstart = (int*)alloc((size_t)(N_GRAPHS + 1) * 4);

  // layer-2 input, pre-split bf16 hi/lo — ALIASES x2_buf (disjoint
  // lifetimes: x2H/x2L dead after gemm2 consumes them; agg2 then
  // overwrites x2_buf entirely before pool reads it).
  short* x2H = (short*)x2_buf;
  short* x2L = x2H + (size_t)N_NODES * FEAT;

  (void)hipMemsetAsync(gbcnt, 0, (size_t)(NBUCKET + 1) * 4, stream);
  wsplit_pass1_kernel<<<512 + P1_BLOCKS, 256, 0, stream>>>(
      W1, W2, WtH1, WtL1, WtH2, WtL2, src, dst, gbcnt, bdata);
  bucketscan_kernel<<<1, 256, 0, stream>>>(gbcnt, gboffs, offs, batch, gstart);

  // layer 1: gemm rows y<GY; pass-2 scatter buckets at the grid TAIL
  dim3 g1(2, GY + (NBUCKET + 1) / 2);  // 2 x 587
  gemm_mfma_kernel<4, true, false><<<g1, 256, 0, stream>>>(
      x, nullptr, nullptr, WtH1, WtL1, h16, att_s1, att_d1, as_buf, ad_buf,
      N_NODES, bdata, gbcnt, gboffs, offs, ssrc);
  agg_kernel<64, true><<<(N_NODES + 3) / 4, 256, 0, stream>>>(
      h16, as_buf, ad_buf, offs, ssrc, b1, nullptr, x2H, x2L, as2, ad2);
  // layer 2: H=1 (as2/ad2 pre-zeroed by layer-1 agg), pre-split input
  dim3 g2(2, GY);
  gemm_mfma_kernel<1, false, true><<<g2, 256, 0, stream>>>(
      nullptr, x2H, x2L, WtH2, WtL2, h16, att_s2, att_d2, as2, ad2,
      N_NODES, nullptr, nullptr, nullptr, nullptr, nullptr);
  agg_kernel<256, false><<<(N_NODES + 3) / 4, 256, 0, stream>>>(
      h16, as2, ad2, offs, ssrc, b2, x2_buf, nullptr, nullptr,
      nullptr, nullptr);
  pool_partial_kernel<<<dim3(N_GRAPHS, POOL_PARTS), 256, 0, stream>>>(x2_buf, gstart, part);
  poolfc_kernel<<<N_GRAPHS, 256, 0, stream>>>(part, gstart, Wfc, bfc, outp);
}

// Round 9
// 380.133 us; speedup vs baseline: 1.2585x; 1.2585x over previous
//
#include <hip/hip_runtime.h>
#include <hip/hip_bf16.h>
#include <cfloat>

#define N_NODES 50000
#define N_EDGES 800000
#define N_GRAPHS 50
#define FEAT 256
#define NEG_SLOPE 0.2f

#define NBUCKET 391   // ceil(50000/128); bucket b = dst >> 7
#define BCAP 3072     // capacity per bucket (mean 2046, sd ~45)
#define P1_EDGES 8192
#define P1_BLOCKS 98  // 98*8192 = 802816 >= 800000

typedef __attribute__((ext_vector_type(8))) short short8;
typedef __attribute__((ext_vector_type(4))) short shortx4;
typedef __attribute__((ext_vector_type(4))) float floatx4;

constexpr int GY = (N_NODES + 127) / 128;  // 391 gemm y-rows

__device__ __forceinline__ float lrelu(float e) {
  return e > 0.f ? e : NEG_SLOPE * e;
}
__device__ __forceinline__ short f2bf(float f) {
  __hip_bfloat16 b = __float2bfloat16(f);
  return *(short*)&b;
}
__device__ __forceinline__ float bf2f(short s) {
  unsigned u = ((unsigned)(unsigned short)s) << 16;
  return __uint_as_float(u);
}

// ---- W prep (blocks 0..511) + pass-1 edge binning (blocks 512..609) ----
__global__ __launch_bounds__(256) void wsplit_pass1_kernel(
    const float* __restrict__ W1, const float* __restrict__ W2,
    short* __restrict__ H1, short* __restrict__ L1,
    short* __restrict__ H2, short* __restrict__ L2,
    const int* __restrict__ src, const int* __restrict__ dst,
    int* __restrict__ gbcnt, int* __restrict__ bdata) {
  int b = blockIdx.x, t = threadIdx.x;
  if (b < 512) {
    const float* W = (b < 256) ? W1 : W2;
    short* Hp = (b < 256) ? H1 : H2;
    short* Lp = (b < 256) ? L1 : L2;
    int k = b & 255;
    float v = W[k * 256 + t];
    short h = f2bf(v);
    Hp[t * 256 + k] = h;
    Lp[t * 256 + k] = f2bf(v - bf2f(h));
    return;
  }
  __shared__ int bb[NBUCKET];
  int base = (b - 512) * P1_EDGES;
  for (int i = t; i < NBUCKET; i += 256) bb[i] = 0;
  __syncthreads();
#pragma unroll 4
  for (int j = 0; j < P1_EDGES / 256; j++) {
    int e = base + j * 256 + t;
    if (e < N_EDGES) atomicAdd(&bb[dst[e] >> 7], 1);
  }
  __syncthreads();
  for (int i = t; i < NBUCKET; i += 256) {
    int c = bb[i];
    bb[i] = (c > 0) ? atomicAdd(&gbcnt[i], c) : 0;
  }
  __syncthreads();
#pragma unroll 4
  for (int j = 0; j < P1_EDGES / 256; j++) {
    int e = base + j * 256 + t;
    if (e < N_EDGES) {
      int d = dst[e];
      int bk = d >> 7;
      int p = atomicAdd(&bb[bk], 1);
      if (p < BCAP) bdata[bk * BCAP + p] = (src[e] << 7) | (d & 127);
    }
  }
}

// ---- exclusive scan of 391 bucket counts + graph bounds ----
__global__ __launch_bounds__(256) void bucketscan_kernel(
    const int* __restrict__ gbcnt, int* __restrict__ gboffs,
    int* __restrict__ offs, const int* __restrict__ batch,
    int* __restrict__ gstart) {
  __shared__ int s[512];
  int t = threadIdx.x;
  s[t] = (t < NBUCKET) ? gbcnt[t] : 0;
  s[t + 256] = (t + 256 < NBUCKET) ? gbcnt[t + 256] : 0;
  __syncthreads();
  for (int off = 1; off < 512; off <<= 1) {
    int v0 = (t >= off) ? s[t - off] : 0;
    int v1 = (t + 256 >= off) ? s[t + 256 - off] : 0;
    __syncthreads();
    s[t] += v0;
    s[t + 256] += v1;
    __syncthreads();
  }
  if (t < NBUCKET) gboffs[t] = (t == 0) ? 0 : s[t - 1];
  if (t + 256 < NBUCKET) gboffs[t + 256] = s[t + 255];
  if (t == 0) {
    gboffs[NBUCKET] = s[NBUCKET - 1];
    offs[N_NODES] = s[NBUCKET - 1];
  }
  if (t <= N_GRAPHS) {
    int lo = 0, hi = N_NODES;
    while (lo < hi) {
      int mid = (lo + hi) >> 1;
      if (batch[mid] < t) lo = mid + 1; else hi = mid;
    }
    gstart[t] = lo;
  }
}

// ---- MFMA GEMM + fused attention dots; tail scatter (R14 verified) ----
template <int H, bool SCATTER, bool SPLIT_IN>
__global__ __launch_bounds__(256) void gemm_mfma_kernel(
    const float* __restrict__ A, const short* __restrict__ AH,
    const short* __restrict__ AL,
    const short* __restrict__ WtH, const short* __restrict__ WtL,
    short* __restrict__ C16,
    const float* __restrict__ att_src, const float* __restrict__ att_dst,
    float* __restrict__ a_src, float* __restrict__ a_dst, int M,
    const int* __restrict__ bdata, const int* __restrict__ gbcnt,
    const int* __restrict__ gboffs, int* __restrict__ offs,
    int* __restrict__ ssrc) {
  __shared__ __align__(16) char smem[32768];
  auto AsH = (short(*)[32])(smem);
  auto AsL = (short(*)[32])(smem + 8192);
  auto BsH = (short(*)[32])(smem + 16384);
  auto BsL = (short(*)[32])(smem + 24576);
  int t = threadIdx.x;
  int yb = blockIdx.y;
  if constexpr (SCATTER) {
    if (yb >= GY) {
      int bkt = (yb - GY) * 2 + blockIdx.x;  // 0..391
      if (bkt >= NBUCKET) return;
      int nbase = bkt * 128;
      int nn = N_NODES - nbase; if (nn > 128) nn = 128;
      int cb = gbcnt[bkt]; if (cb > BCAP) cb = BCAP;
      int gb = gboffs[bkt];
      int* hist = (int*)smem;        // [128]
      int* cur = hist + 128;         // [128]
      int* stage = cur + 128;        // [3072]
      if (t < 128) hist[t] = 0;
      __syncthreads();
      const int* bd = bdata + bkt * BCAP;
      for (int i = t; i < cb; i += 256) atomicAdd(&hist[bd[i] & 127], 1);
      __syncthreads();
      if (t < 128) cur[t] = hist[t];
      __syncthreads();
      for (int off = 1; off < 128; off <<= 1) {
        int v = (t >= off && t < 128) ? cur[t - off] : 0;
        __syncthreads();
        if (t < 128) cur[t] += v;
        __syncthreads();
      }
      if (t < 128) {
        int excl = cur[t] - hist[t];
        if (t < nn) offs[nbase + t] = gb + excl;
        cur[t] = excl;  // local cursor
      }
      __syncthreads();
      for (int i = t; i < cb; i += 256) {
        int w = bd[i];
        int p = atomicAdd(&cur[w & 127], 1);
        stage[p] = w >> 7;
      }
      __syncthreads();
      for (int i = t; i < cb; i += 256) ssrc[gb + i] = stage[i];
      return;
    }
  }
  int bm = yb * 128, bn = blockIdx.x * 128;
  int w = t >> 6, lane = t & 63;
  int wrow = (w & 1) * 64, wcol = (w >> 1) * 64;
  int m15 = lane & 15, q = lane >> 4;
  int sr = t >> 1, sk = (t & 1) * 16;
  int g3 = (sr >> 1) & 3;
  int c0 = (((sk >> 3) + 0) ^ g3) * 8;
  int c1 = (((sk >> 3) + 1) ^ g3) * 8;
  floatx4 acc[4][4] = {};
  int arow = bm + sr;
  for (int k0 = 0; k0 < 256; k0 += 32) {
    int4 ah0, ah1, al0, al1;
    if constexpr (SPLIT_IN) {
      if (arow < M) {
        const short* Hp = AH + (size_t)arow * 256 + k0 + sk;
        const short* Lp = AL + (size_t)arow * 256 + k0 + sk;
        ah0 = *(const int4*)(Hp + 0);
        ah1 = *(const int4*)(Hp + 8);
        al0 = *(const int4*)(Lp + 0);
        al1 = *(const int4*)(Lp + 8);
      } else {
        ah0 = ah1 = al0 = al1 = make_int4(0, 0, 0, 0);
      }
    } else {
      float4 a0 = make_float4(0.f, 0.f, 0.f, 0.f), a1 = a0, a2 = a0, a3 = a0;
      if (arow < M) {
        const float* Ap = A + (size_t)arow * 256 + k0 + sk;
        a0 = *(const float4*)(Ap + 0);
        a1 = *(const float4*)(Ap + 4);
        a2 = *(const float4*)(Ap + 8);
        a3 = *(const float4*)(Ap + 12);
      }
      float af[16];
      *(float4*)&af[0] = a0; *(float4*)&af[4] = a1;
      *(float4*)&af[8] = a2; *(float4*)&af[12] = a3;
      short th[16], tl[16];
#pragma unroll
      for (int j = 0; j < 16; j++) {
        short h = f2bf(af[j]);
        th[j] = h;
        tl[j] = f2bf(af[j] - bf2f(h));
      }
      ah0 = *(int4*)&th[0]; ah1 = *(int4*)&th[8];
      al0 = *(int4*)&tl[0]; al1 = *(int4*)&tl[8];
    }
    const short* BHp = WtH + (size_t)(bn + sr) * 256 + k0 + sk;
    const short* BLp = WtL + (size_t)(bn + sr) * 256 + k0 + sk;
    int4 bh0 = *(const int4*)(BHp);
    int4 bh1 = *(const int4*)(BHp + 8);
    int4 bl0 = *(const int4*)(BLp);
    int4 bl1 = *(const int4*)(BLp + 8);
    __syncthreads();
    *(int4*)&AsH[sr][c0] = ah0;
    *(int4*)&AsH[sr][c1] = ah1;
    *(int4*)&AsL[sr][c0] = al0;
    *(int4*)&AsL[sr][c1] = al1;
    *(int4*)&BsH[sr][c0] = bh0;
    *(int4*)&BsH[sr][c1] = bh1;
    *(int4*)&BsL[sr][c0] = bl0;
    *(int4*)&BsL[sr][c1] = bl1;
    __syncthreads();
    short8 Bh[4], Bl[4];
#pragma unroll
    for (int c = 0; c < 4; c++) {
      int Rb = wcol + c * 16 + m15;
      int sw = (q ^ ((Rb >> 1) & 3)) * 8;
      Bh[c] = *(const short8*)&BsH[Rb][sw];
      Bl[c] = *(const short8*)&BsL[Rb][sw];
    }
#pragma unroll
    for (int r = 0; r < 4; r++) {
      int Ra = wrow + r * 16 + m15;
      int sw = (q ^ ((Ra >> 1) & 3)) * 8;
      short8 Ah = *(const short8*)&AsH[Ra][sw];
      short8 Al = *(const short8*)&AsL[Ra][sw];
#pragma unroll
      for (int c = 0; c < 4; c++) {
        acc[r][c] = __builtin_amdgcn_mfma_f32_16x16x32_bf16(Ah, Bh[c], acc[r][c], 0, 0, 0);
        acc[r][c] = __builtin_amdgcn_mfma_f32_16x16x32_bf16(Ah, Bl[c], acc[r][c], 0, 0, 0);
        acc[r][c] = __builtin_amdgcn_mfma_f32_16x16x32_bf16(Al, Bh[c], acc[r][c], 0, 0, 0);
      }
    }
  }
  float asv[4], adv[4];
#pragma unroll
  for (int c = 0; c < 4; c++) {
    int col = bn + wcol + c * 16 + m15;
    asv[c] = att_src[col];
    adv[c] = att_dst[col];
  }
#pragma unroll
  for (int r = 0; r < 4; r++) {
#pragma unroll
    for (int p = 0; p < 4; p++) {
      int grow = bm + wrow + r * 16 + q * 4 + p;
      float s = acc[r][0][p] * asv[0] + acc[r][1][p] * asv[1] +
                acc[r][2][p] * asv[2] + acc[r][3][p] * asv[3];
      float d = acc[r][0][p] * adv[0] + acc[r][1][p] * adv[1] +
                acc[r][2][p] * adv[2] + acc[r][3][p] * adv[3];
#pragma unroll
      for (int o = 1; o < 16; o <<= 1) {
        s += __shfl_xor(s, o, 64);
        d += __shfl_xor(d, o, 64);
      }
      if (grow < M) {
        if (m15 == 0) {
          if constexpr (H == 4) {
            int head = (bn >> 6) + (wcol >> 6);
            a_src[grow * 4 + head] = s;
            a_dst[grow * 4 + head] = d;
          } else {
            atomicAdd(&a_src[grow], s);
            atomicAdd(&a_dst[grow], d);
          }
        }
#pragma unroll
        for (int c = 0; c < 4; c++) {
          int gcol = bn + wcol + c * 16 + m15;
          C16[(size_t)grow * 256 + gcol] = f2bf(acc[r][c][p]);
        }
      }
    }
  }
}

// ---- fused aggregate: in-register softmax, 2x4 register-neutral pipe ----
// R16: R15's 1-group-ahead pipeline crossed the 64-VGPR cliff (36->68,
// waves/SIMD 8->4, agg 70->110us). Same total edge state (32 regs) is
// here split into TWO statically-named 4-edge buffers A/B in a modulo-2
// schedule: compute(k) overlaps gathers(k+1); ssrc prefetched one
// subgroup further (breaks the s->gather chain). No copies, no dynamic
// indexing, no register growth.
template <int CH, bool SPLIT_OUT>
__global__ __launch_bounds__(256) void agg_kernel(
    const short* __restrict__ h16, const float* __restrict__ a_src,
    const float* __restrict__ a_dst, const int* __restrict__ offs,
    const int* __restrict__ ssrc, const float* __restrict__ bias,
    float* __restrict__ out, short* __restrict__ outH,
    short* __restrict__ outL, float* __restrict__ z1,
    float* __restrict__ z2) {
  constexpr int H = 256 / CH;
  int n = blockIdx.x * 4 + (threadIdx.x >> 6);
  int lane = threadIdx.x & 63;
  if (n >= N_NODES) return;
  int head = (4 * lane) / CH;
  int start = offs[n], end = offs[n + 1];
  float adv = a_dst[n * H + head];
  if (z1 != nullptr && lane == 0) { z1[n] = 0.f; z2[n] = 0.f; }
  float l = 0.f;
  float acc0 = 0.f, acc1 = 0.f, acc2 = 0.f, acc3 = 0.f;

  auto loadS = [&](int base, int (&s)[4]) {
#pragma unroll
    for (int j = 0; j < 4; j++) s[j] = ssrc[base + j];
  };
  auto loadU = [&](const int (&s)[4], uint2 (&u)[4], float (&av)[4]) {
#pragma unroll
    for (int j = 0; j < 4; j++)
      u[j] = *(const uint2*)(h16 + (size_t)s[j] * 256 + 4 * lane);
#pragma unroll
    for (int j = 0; j < 4; j++) av[j] = a_src[s[j] * H + head];
  };
  auto comp = [&](const uint2 (&u)[4], const float (&av)[4]) {
#pragma unroll
    for (int j = 0; j < 4; j++) {
      float p = __expf(lrelu(av[j] + adv));
      l += p;
      acc0 = fmaf(p, __uint_as_float(u[j].x << 16), acc0);
      acc1 = fmaf(p, __uint_as_float(u[j].x & 0xffff0000u), acc1);
      acc2 = fmaf(p, __uint_as_float(u[j].y << 16), acc2);
      acc3 = fmaf(p, __uint_as_float(u[j].y & 0xffff0000u), acc3);
    }
  };

  int i = start;
  int n4 = (end - start) >> 2;
  if (n4 > 0) {
    int sA[4], sB[4];
    uint2 uA[4], uB[4];
    float avA[4], avB[4];
    loadS(i, sA);
    if (n4 > 1) loadS(i + 4, sB);
    loadU(sA, uA, avA);  // gathers grp 0 in flight
    int k = 0;
    for (; k + 2 <= n4; k += 2) {
      loadU(sB, uB, avB);                        // gathers k+1 in flight
      if (k + 2 < n4) loadS(i + 4 * (k + 2), sA);  // s for k+2 (sA dead)
      comp(uA, avA);                             // compute k, covers k+1
      if (k + 2 < n4) loadU(sA, uA, avA);        // gathers k+2 in flight
      if (k + 3 < n4) loadS(i + 4 * (k + 3), sB);  // s for k+3 (sB dead)
      comp(uB, avB);                             // compute k+1, covers k+2
    }
    if (k < n4) comp(uA, avA);                   // odd n4 leftover
    i += n4 * 4;
  }
  for (; i < end; i++) {
    int s = ssrc[i];
    uint2 u = *(const uint2*)(h16 + (size_t)s * 256 + 4 * lane);
    float p = __expf(lrelu(a_src[s * H + head] + adv));
    l += p;
    acc0 = fmaf(p, __uint_as_float(u.x << 16), acc0);
    acc1 = fmaf(p, __uint_as_float(u.x & 0xffff0000u), acc1);
    acc2 = fmaf(p, __uint_as_float(u.y << 16), acc2);
    acc3 = fmaf(p, __uint_as_float(u.y & 0xffff0000u), acc3);
  }
  float ilv = l > 0.f ? 1.f / l : 0.f;
  float4 bv = *(const float4*)(bias + 4 * lane);
  float ox = fmaxf(fmaf(acc0, ilv, bv.x), 0.f);
  float oy = fmaxf(fmaf(acc1, ilv, bv.y), 0.f);
  float oz = fmaxf(fmaf(acc2, ilv, bv.z), 0.f);
  float ow = fmaxf(fmaf(acc3, ilv, bv.w), 0.f);
  if constexpr (SPLIT_OUT) {
    shortx4 hv, lv;
    hv.x = f2bf(ox); lv.x = f2bf(ox - bf2f(hv.x));
    hv.y = f2bf(oy); lv.y = f2bf(oy - bf2f(hv.y));
    hv.z = f2bf(oz); lv.z = f2bf(oz - bf2f(hv.z));
    hv.w = f2bf(ow); lv.w = f2bf(ow - bf2f(hv.w));
    *(shortx4*)(outH + (size_t)n * 256 + 4 * lane) = hv;
    *(shortx4*)(outL + (size_t)n * 256 + 4 * lane) = lv;
  } else {
    float4 o;
    o.x = ox; o.y = oy; o.z = oz; o.w = ow;
    *(float4*)(out + (size_t)n * 256 + 4 * lane) = o;
  }
}

// ---- global mean pool + FC ----
#define POOL_PARTS 16
__global__ __launch_bounds__(256) void pool_partial_kernel(
    const float* __restrict__ h, const int* __restrict__ gstart,
    float* __restrict__ part) {
  int g = blockIdx.x, p = blockIdx.y, t = threadIdx.x;
  int s = gstart[g], e = gstart[g + 1];
  float acc = 0.f;
  for (int n = s + p; n < e; n += POOL_PARTS) acc += h[(size_t)n * 256 + t];
  part[((size_t)g * POOL_PARTS + p) * 256 + t] = acc;
}

__global__ __launch_bounds__(256) void poolfc_kernel(
    const float* __restrict__ part, const int* __restrict__ gstart,
    const float* __restrict__ W, const float* __restrict__ b,
    float* __restrict__ out) {
  int g = blockIdx.x, t = threadIdx.x;
  __shared__ float ps[256];
  float acc = 0.f;
#pragma unroll
  for (int p = 0; p < POOL_PARTS; p++)
    acc += part[((size_t)g * POOL_PARTS + p) * 256 + t];
  int cnt = gstart[g + 1] - gstart[g];
  ps[t] = acc / (float)(cnt > 0 ? cnt : 1);
  __syncthreads();
  float a2 = 0.f;
#pragma unroll 8
  for (int k = 0; k < 256; k++) a2 = fmaf(ps[k], W[k * 256 + t], a2);
  out[g * 256 + t] = fmaxf(a2 + b[t], 0.f);
}

extern "C" void kernel_launch(void* const* d_in, const int* in_sizes, int n_in,
                              void* d_out, int out_size, void* d_ws, size_t ws_size,
                              hipStream_t stream) {
  const float* x      = (const float*)d_in[0];
  const int*   ei     = (const int*)d_in[1];
  const int*   batch  = (const int*)d_in[2];
  const float* W1     = (const float*)d_in[3];
  const float* att_s1 = (const float*)d_in[4];
  const float* att_d1 = (const float*)d_in[5];
  const float* b1     = (const float*)d_in[6];
  const float* W2     = (const float*)d_in[7];
  const float* att_s2 = (const float*)d_in[8];
  const float* att_d2 = (const float*)d_in[9];
  const float* b2     = (const float*)d_in[10];
  const float* Wfc    = (const float*)d_in[11];
  const float* bfc    = (const float*)d_in[12];
  const int* src = ei;
  const int* dst = ei + N_EDGES;
  float* outp = (float*)d_out;

  char* ws = (char*)d_ws;
  size_t off = 0;
  auto alloc = [&](size_t bytes) -> char* {
    char* p = ws + off;
    off += (bytes + 255) & ~(size_t)255;
    return p;
  };
  float* x2_buf = (float*)alloc((size_t)N_NODES * FEAT * 4);
  short* h16    = (short*)alloc((size_t)N_NODES * FEAT * 2);
  float* as_buf = (float*)alloc((size_t)N_NODES * 4 * 4);
  float* ad_buf = (float*)alloc((size_t)N_NODES * 4 * 4);
  float* as2    = (float*)alloc((size_t)N_NODES * 4);
  float* ad2    = (float*)alloc((size_t)N_NODES * 4);
  float* part   = (float*)alloc((size_t)N_GRAPHS * POOL_PARTS * FEAT * 4);
  short* WtH1   = (short*)alloc((size_t)256 * 256 * 2);
  short* WtL1   = (short*)alloc((size_t)256 * 256 * 2);
  short* WtH2   = (short*)alloc((size_t)256 * 256 * 2);
  short* WtL2   = (short*)alloc((size_t)256 * 256 * 2);
  int* offs   = (int*)alloc((size_t)(N_NODES + 1) * 4);
  int* ssrc   = (int*)alloc((size_t)N_EDGES * 4);
  int* bdata  = (int*)alloc((size_t)NBUCKET * BCAP * 4);
  int* gbcnt  = (int*)alloc((size_t)(NBUCKET + 1) * 4);
  int* gboffs = (int*)alloc((size_t)(NBUCKET + 1) * 4);
  int* gstart = (int*)alloc((size_t)(N_GRAPHS + 1) * 4);

  // layer-2 input, pre-split bf16 hi/lo — ALIASES x2_buf (disjoint
  // lifetimes: x2H/x2L dead after gemm2 consumes them; agg2 then
  // overwrites x2_buf entirely before pool reads it).
  short* x2H = (short*)x2_buf;
  short* x2L = x2H + (size_t)N_NODES * FEAT;

  (void)hipMemsetAsync(gbcnt, 0, (size_t)(NBUCKET + 1) * 4, stream);
  wsplit_pass1_kernel<<<512 + P1_BLOCKS, 256, 0, stream>>>(
      W1, W2, WtH1, WtL1, WtH2, WtL2, src, dst, gbcnt, bdata);
  bucketscan_kernel<<<1, 256, 0, stream>>>(gbcnt, gboffs, offs, batch, gstart);

  // layer 1: gemm rows y<GY; pass-2 scatter buckets at the grid TAIL
  dim3 g1(2, GY + (NBUCKET + 1) / 2);  // 2 x 587
  gemm_mfma_kernel<4, true, false><<<g1, 256, 0, stream>>>(
      x, nullptr, nullptr, WtH1, WtL1, h16, att_s1, att_d1, as_buf, ad_buf,
      N_NODES, bdata, gbcnt, gboffs, offs, ssrc);
  agg_kernel<64, true><<<(N_NODES + 3) / 4, 256, 0, stream>>>(
      h16, as_buf, ad_buf, offs, ssrc, b1, nullptr, x2H, x2L, as2, ad2);
  // layer 2: H=1 (as2/ad2 pre-zeroed by layer-1 agg), pre-split input
  dim3 g2(2, GY);
  gemm_mfma_kernel<1, false, true><<<g2, 256, 0, stream>>>(
      nullptr, x2H, x2L, WtH2, WtL2, h16, att_s2, att_d2, as2, ad2,
      N_NODES, nullptr, nullptr, nullptr, nullptr, nullptr);
  agg_kernel<256, false><<<(N_NODES + 3) / 4, 256, 0, stream>>>(
      h16, as2, ad2, offs, ssrc, b2, x2_buf, nullptr, nullptr,
      nullptr, nullptr);
  pool_partial_kernel<<<dim3(N_GRAPHS, POOL_PARTS), 256, 0, stream>>>(x2_buf, gstart, part);
  poolfc_kernel<<<N_GRAPHS, 256, 0, stream>>>(part, gstart, Wfc, bfc, outp);
}